// Round 8
// baseline (576.164 us; speedup 1.0000x reference)
//
#include <hip/hip_runtime.h>
#include <stdint.h>
#include <cmath>

typedef unsigned short u16;
typedef unsigned int u32;
typedef __attribute__((ext_vector_type(8))) __bf16 bf16x8;
typedef __attribute__((ext_vector_type(4))) float f32x4;

#define HIDDEN 4096
#define NH 32
#define NKV 8
#define HD 128
#define S_LEN 2048

__device__ __forceinline__ u16 f2bf(float f) {
    u32 x = __float_as_uint(f);
    x += 0x7fff + ((x >> 16) & 1);   // RNE
    return (u16)(x >> 16);
}
__device__ __forceinline__ float bf2f(u16 u) {
    return __uint_as_float(((u32)u) << 16);
}
__device__ __forceinline__ float fexp2(float x) {
#if __has_builtin(__builtin_amdgcn_exp2f)
    return __builtin_amdgcn_exp2f(x);
#else
    return __expf(x * 0.6931471805599453f);
#endif
}

typedef __attribute__((address_space(1))) const void gv_t;
typedef __attribute__((address_space(3))) void lv_t;
__device__ __forceinline__ void async16(const u16* g, u16* s) {
    __builtin_amdgcn_global_load_lds((gv_t*)g, (lv_t*)s, 16, 0, 0);
}
__device__ __forceinline__ void async16f(const float* g, float* s) {
    __builtin_amdgcn_global_load_lds((gv_t*)g, (lv_t*)s, 16, 0, 0);
}

// ---- f32 tile staging (128 rows x 64 cols f32, 16B chunks, 16-chunk XOR swizzle) ----
// 2048 chunks; 256 threads x 8. Logical chunk g of row r lands at physical sl = g^(r&15).
#define STAGE_F32(SRC, LDK, DST)                                                       \
    _Pragma("unroll") for (int i = 0; i < 8; ++i) {                                    \
        int c = i * 256 + tid;                                                         \
        int r = c >> 4, sl = c & 15, g = sl ^ (r & 15);                                \
        async16f((SRC) + (size_t)r * (LDK) + g * 4, &(DST)[c * 4]);                    \
    }

// frag read from f32 tile: cols ks*32+quad*8 .. +7, RNE-rounded to bf16x8
__device__ __forceinline__ bf16x8 read_f32_frag(const float* sF, int row, int ks, int quad) {
    int ch = ks * 8 + quad * 2, rm = row & 15;
    f32x4 a = *(const f32x4*)&sF[row * 64 + ((ch ^ rm) << 2)];
    f32x4 b = *(const f32x4*)&sF[row * 64 + (((ch + 1) ^ rm) << 2)];
    bf16x8 f;
#pragma unroll
    for (int j = 0; j < 4; ++j) { f[j] = (__bf16)a[j]; f[4 + j] = (__bf16)b[j]; }
    return f;
}

// ---------------- RoPE cos/sin table: f64 precompute ----------------
struct DTab { double f[64]; };
__global__ void rope_table(const int* __restrict__ pos, float2* __restrict__ tab,
                           DTab dt) {
    int idx = blockIdx.x * 256 + threadIdx.x;   // < 2048*64
    int d = idx & 63, s = idx >> 6;
    double fr = (double)pos[s] * dt.f[d];
    double sd, cd;
    sincos(fr, &sd, &cd);
    tab[idx] = make_float2((float)cd, (float)sd);
}

// ---------------- fused QKV projection, f32-direct operands ----------------
// A = hs f32 [2048,4096]; B = wq|wk|wv f32 rows (block-uniform select).
// q path -> qb bf16; k path -> fused RoPE via sT pair-exchange; v path -> vt transposed.
__global__ __launch_bounds__(256, 2) void gemm_qkv(
    const float* __restrict__ A, const float* __restrict__ Wq,
    const float* __restrict__ Wk, const float* __restrict__ Wv,
    u16* __restrict__ qb, u16* __restrict__ kbuf, u16* __restrict__ vt,
    const float2* __restrict__ tab)
{
    __shared__ __align__(16) float sMemF[2][128 * 64];   // 64 KB
    float* const sA = sMemF[0];
    float* const sB = sMemF[1];
    const int tid = threadIdx.x;
    const int w = tid >> 6, lane = tid & 63;
    const int l15 = lane & 15, quad = lane >> 4;
    const int m0 = blockIdx.y * 128, n0 = blockIdx.x * 128;
    const int wm = w & 1, wn = w >> 1;

    const float* Bp; int nb;
    if (n0 < 4096)      { Bp = Wq; nb = n0; }
    else if (n0 < 5120) { Bp = Wk; nb = n0 - 4096; }
    else                { Bp = Wv; nb = n0 - 5120; }

    f32x4 acc[4][4];
#pragma unroll
    for (int mi = 0; mi < 4; ++mi)
#pragma unroll
        for (int ni = 0; ni < 4; ++ni)
#pragma unroll
            for (int r = 0; r < 4; ++r) acc[mi][ni][r] = 0.f;

    for (int kt = 0; kt < HIDDEN; kt += 64) {
        STAGE_F32(A + (size_t)m0 * HIDDEN + kt, HIDDEN, sA)
        STAGE_F32(Bp + (size_t)nb * HIDDEN + kt, HIDDEN, sB)
        __syncthreads();
#pragma unroll
        for (int ks = 0; ks < 2; ++ks) {
            bf16x8 af[4], bf[4];
#pragma unroll
            for (int t = 0; t < 4; ++t)
                af[t] = read_f32_frag(sA, wm * 64 + t * 16 + l15, ks, quad);
#pragma unroll
            for (int t = 0; t < 4; ++t)
                bf[t] = read_f32_frag(sB, wn * 64 + t * 16 + l15, ks, quad);
#pragma unroll
            for (int mi = 0; mi < 4; ++mi)
#pragma unroll
                for (int ni = 0; ni < 4; ++ni)
                    acc[mi][ni] = __builtin_amdgcn_mfma_f32_16x16x32_bf16(
                        af[mi], bf[ni], acc[mi][ni], 0, 0, 0);
        }
        __syncthreads();
    }

    if (n0 < 4096) {          // q path: raw projection, row-major bf16 (rope in attn)
#pragma unroll
        for (int mi = 0; mi < 4; ++mi) {
            int row = m0 + wm * 64 + mi * 16 + quad * 4;
#pragma unroll
            for (int ni = 0; ni < 4; ++ni) {
                int col = n0 + wn * 64 + ni * 16 + l15;
#pragma unroll
                for (int r = 0; r < 4; ++r)
                    qb[(size_t)(row + r) * HIDDEN + col] = f2bf(acc[mi][ni][r]);
            }
        }
    } else if (n0 < 5120) {   // k path: fused RoPE via LDS pair-exchange
        u16* const sT = (u16*)sMemF;  // 128x128 bf16 = 32 KB (main loop done)
        int cb = n0 - 4096;
#pragma unroll
        for (int mi = 0; mi < 4; ++mi)
#pragma unroll
            for (int ni = 0; ni < 4; ++ni) {
                int cl = wn * 64 + ni * 16 + l15;
#pragma unroll
                for (int r = 0; r < 4; ++r) {
                    int rl = wm * 64 + mi * 16 + quad * 4 + r;
                    sT[rl * 128 + cl] = f2bf(acc[mi][ni][r]);
                }
            }
        __syncthreads();
#pragma unroll
        for (int mi = 0; mi < 4; ++mi)
#pragma unroll
            for (int ni = 0; ni < 4; ++ni) {
                int cl = wn * 64 + ni * 16 + l15;   // = within-head d (cb mult of 128)
#pragma unroll
                for (int r = 0; r < 4; ++r) {
                    int rl = wm * 64 + mi * 16 + quad * 4 + r;
                    int srow = m0 + rl;
                    float x1 = bf2f(sT[rl * 128 + cl]);
                    float x2 = bf2f(sT[rl * 128 + (cl ^ 64)]);
                    float2 cs = tab[(size_t)srow * 64 + (cl & 63)];
                    float o = (cl < 64) ? (x1 * cs.x - x2 * cs.y)
                                        : (x1 * cs.x + x2 * cs.y);
                    kbuf[(size_t)srow * (NKV * HD) + cb + cl] = f2bf(o);
                }
            }
    } else {                  // v path: transposed vt[c][s]
        int cb = n0 - 5120;
#pragma unroll
        for (int mi = 0; mi < 4; ++mi) {
            int row = m0 + wm * 64 + mi * 16 + quad * 4;
#pragma unroll
            for (int ni = 0; ni < 4; ++ni) {
                int c = cb + wn * 64 + ni * 16 + l15;
                union { u16 u[4]; uint2 v; } pk;
#pragma unroll
                for (int r = 0; r < 4; ++r) pk.u[r] = f2bf(acc[mi][ni][r]);
                *(uint2*)&vt[(size_t)c * S_LEN + row] = pk.v;
            }
        }
    }
}

// ---------------- O-projection: A bf16 [2048,4096], B = wo f32 [4096,4096], C f32 ----
__global__ __launch_bounds__(256, 2) void gemm_bt_f32(
    const u16* __restrict__ A, const float* __restrict__ B, float* __restrict__ C,
    int N, int K)
{
    __shared__ __align__(16) u16 sA[128 * 64];           // 16 KB
    __shared__ __align__(16) float sB[128 * 64];         // 32 KB
    const int tid = threadIdx.x;
    const int w = tid >> 6, lane = tid & 63;
    const int l15 = lane & 15, quad = lane >> 4;
    const int m0 = blockIdx.y * 128, n0 = blockIdx.x * 128;
    const int wm = w & 1, wn = w >> 1;

    f32x4 acc[4][4];
#pragma unroll
    for (int mi = 0; mi < 4; ++mi)
#pragma unroll
        for (int ni = 0; ni < 4; ++ni)
#pragma unroll
            for (int r = 0; r < 4; ++r) acc[mi][ni][r] = 0.f;

    for (int kt = 0; kt < K; kt += 64) {
#pragma unroll
        for (int i = 0; i < 4; ++i) {      // A tile: bf16, 8-chunk swizzle (proven path)
            int c = (i * 4 + w) * 64 + lane;
            int r = c >> 3, sl = c & 7, g = sl ^ (r & 7);
            async16(A + (size_t)(m0 + r) * K + kt + g * 8, &sA[c * 8]);
        }
        STAGE_F32(B + (size_t)n0 * K + kt, K, sB)
        __syncthreads();
#pragma unroll
        for (int ks = 0; ks < 2; ++ks) {
            bf16x8 af[4], bf[4];
#pragma unroll
            for (int t = 0; t < 4; ++t) {
                int row = wm * 64 + t * 16 + l15;
                int sl = (ks * 4 + quad) ^ (row & 7);
                af[t] = *(const bf16x8*)&sA[row * 64 + sl * 8];
            }
#pragma unroll
            for (int t = 0; t < 4; ++t)
                bf[t] = read_f32_frag(sB, wn * 64 + t * 16 + l15, ks, quad);
#pragma unroll
            for (int mi = 0; mi < 4; ++mi)
#pragma unroll
                for (int ni = 0; ni < 4; ++ni)
                    acc[mi][ni] = __builtin_amdgcn_mfma_f32_16x16x32_bf16(
                        af[mi], bf[ni], acc[mi][ni], 0, 0, 0);
        }
        __syncthreads();
    }
#pragma unroll
    for (int mi = 0; mi < 4; ++mi) {
        int row = m0 + wm * 64 + mi * 16 + quad * 4;
#pragma unroll
        for (int ni = 0; ni < 4; ++ni) {
            int col = n0 + wn * 64 + ni * 16 + l15;
#pragma unroll
            for (int r = 0; r < 4; ++r)
                C[(size_t)(row + r) * N + col] = acc[mi][ni][r];
        }
    }
}

// ---------------- flash attention ----------------
// v7 core (swapped QK^T, register P via k-permutation sigma, dbuf K/V, one
// barrier/tile, defer-rescale) + fused Q-RoPE in the prologue.
__global__ __launch_bounds__(256, 2) void attn_kernel(
    const u16* __restrict__ Q, const u16* __restrict__ Kb,
    const u16* __restrict__ Vt, u16* __restrict__ O,
    const float2* __restrict__ tab, float qscale)
{
    __shared__ u16 sK[2][64 * 128];                  // 2 x 16 KB
    __shared__ u16 sV[2][128 * 64];                  // 2 x 16 KB

    const int tid = threadIdx.x;
    const int w = tid >> 6, lane = tid & 63;
    const int l15 = lane & 15, quad = lane >> 4;
    const int h = blockIdx.y, q0 = blockIdx.x * 128;
    const int hk = h >> 2;

    // Q frags (B-operand: n=lane&15, k=quad*8+j), RoPE + sm_scale*log2e fused.
    bf16x8 qf[2][4];
#pragma unroll
    for (int mt = 0; mt < 2; ++mt) {
        int srow = q0 + w * 32 + mt * 16 + l15;
        const u16* qrow = Q + (size_t)srow * HIDDEN + h * HD;
        bf16x8 raw[4];
#pragma unroll
        for (int ks = 0; ks < 4; ++ks)
            raw[ks] = *(const bf16x8*)(qrow + ks * 32 + quad * 8);
#pragma unroll
        for (int a = 0; a < 2; ++a) {
            const float2* tp = &tab[(size_t)srow * 64 + a * 32 + quad * 8];
#pragma unroll
            for (int j = 0; j < 8; ++j) {
                float c = tp[j].x * qscale, sn = tp[j].y * qscale;
                float x1 = (float)raw[a][j], x2 = (float)raw[a + 2][j];
                qf[mt][a][j]     = (__bf16)(x1 * c - x2 * sn);
                qf[mt][a + 2][j] = (__bf16)(x2 * c + x1 * sn);
            }
        }
    }

    f32x4 oc[8][2];
#pragma unroll
    for (int dt = 0; dt < 8; ++dt)
#pragma unroll
        for (int nt = 0; nt < 2; ++nt)
#pragma unroll
            for (int r = 0; r < 4; ++r) oc[dt][nt][r] = 0.f;
    float m_r[2], l_r[2];
#pragma unroll
    for (int mt = 0; mt < 2; ++mt) { m_r[mt] = -1e30f; l_r[mt] = 0.f; }

    // staging: 1024 chunks of 16B per tile, 256 threads x 4; XOR swizzle.
    auto stageK = [&](int k0, u16* dst) {
#pragma unroll
        for (int i = 0; i < 4; ++i) {
            int c = i * 256 + tid;
            int r = c >> 4, sl = c & 15, g = sl ^ (r & 15);
            async16(Kb + (size_t)(k0 + r) * (NKV * HD) + hk * HD + g * 8, &dst[c * 8]);
        }
    };
    auto stageV = [&](int k0, u16* dst) {
#pragma unroll
        for (int i = 0; i < 4; ++i) {
            int c = i * 256 + tid;
            int r = c >> 3, sl = c & 7, g = sl ^ (r & 7);
            async16(Vt + (size_t)(hk * HD + r) * S_LEN + k0 + g * 8, &dst[c * 8]);
        }
    };

    stageK(0, sK[0]);
    stageV(0, sV[0]);
    __syncthreads();

    int cur = 0;
    for (int kbi = 0; kbi < 32; ++kbi) {
        if (kbi < 31) {
            stageK((kbi + 1) * 64, sK[cur ^ 1]);
            stageV((kbi + 1) * 64, sV[cur ^ 1]);
        }
        const u16* sKc = sK[cur];
        const u16* sVc = sV[cur];

        // ---- S^T = K Q^T : sa[ntk][mt] col=q_local(l15), row=k_local(quad*4+r) ----
        f32x4 sa[4][2];
#pragma unroll
        for (int nt = 0; nt < 4; ++nt)
#pragma unroll
            for (int mt = 0; mt < 2; ++mt)
#pragma unroll
                for (int r = 0; r < 4; ++r) sa[nt][mt][r] = 0.f;
#pragma unroll
        for (int ks = 0; ks < 4; ++ks) {
            bf16x8 kf[4];
#pragma unroll
            for (int nt = 0; nt < 4; ++nt) {
                int row = nt * 16 + l15;
                int sl = (ks * 4 + quad) ^ (row & 15);
                kf[nt] = *(const bf16x8*)&sKc[row * 128 + sl * 8];
            }
#pragma unroll
            for (int nt = 0; nt < 4; ++nt)
#pragma unroll
                for (int mt = 0; mt < 2; ++mt)
                    sa[nt][mt] = __builtin_amdgcn_mfma_f32_16x16x32_bf16(
                        kf[nt], qf[mt][ks], sa[nt][mt], 0, 0, 0);
        }

        // ---- online softmax: per-lane row stats for q = mt*16 + l15 ----
        float mxv[2];
        bool grow = false;
#pragma unroll
        for (int mt = 0; mt < 2; ++mt) {
            float mx = sa[0][mt][0];
#pragma unroll
            for (int nt = 0; nt < 4; ++nt)
#pragma unroll
                for (int r = 0; r < 4; ++r)
                    if (nt || r) mx = fmaxf(mx, sa[nt][mt][r]);
            mx = fmaxf(mx, __shfl_xor(mx, 16));
            mx = fmaxf(mx, __shfl_xor(mx, 32));
            mxv[mt] = mx;
            grow = grow || (mx > m_r[mt] + 8.f);
        }
        const int dorescale = __any((int)grow);   // wave-uniform
        if (dorescale) {
            float al[2];
#pragma unroll
            for (int mt = 0; mt < 2; ++mt) {
                float mnew = fmaxf(m_r[mt], mxv[mt]);
                al[mt] = fexp2(m_r[mt] - mnew);
                m_r[mt] = mnew;
                l_r[mt] *= al[mt];
            }
#pragma unroll
            for (int dt = 0; dt < 8; ++dt)
#pragma unroll
                for (int r = 0; r < 4; ++r) { oc[dt][0][r] *= al[0]; oc[dt][1][r] *= al[1]; }
        }

        // ---- P = exp2(S - m) -> bf16, assembled per sigma (same lane, reg only) ----
        bf16x8 pf[2][2];   // [ks][ntq]
#pragma unroll
        for (int mt = 0; mt < 2; ++mt) {
            float mm = m_r[mt];
            float lsum = 0.f;
#pragma unroll
            for (int ntk = 0; ntk < 4; ++ntk) {
                float p0 = fexp2(sa[ntk][mt][0] - mm);
                float p1 = fexp2(sa[ntk][mt][1] - mm);
                float p2 = fexp2(sa[ntk][mt][2] - mm);
                float p3 = fexp2(sa[ntk][mt][3] - mm);
                lsum += (p0 + p1) + (p2 + p3);
                const int kx = ntk >> 1, e = (ntk & 1) * 4;
                pf[kx][mt][e + 0] = (__bf16)p0;
                pf[kx][mt][e + 1] = (__bf16)p1;
                pf[kx][mt][e + 2] = (__bf16)p2;
                pf[kx][mt][e + 3] = (__bf16)p3;
            }
            l_r[mt] += lsum;   // lane-partial; reduced across quads at finalize
        }

        // ---- O^T += V^T P^T, V read k-permuted by sigma (2x 8B per frag) ----
#pragma unroll
        for (int ks = 0; ks < 2; ++ks) {
#pragma unroll
            for (int dt = 0; dt < 8; ++dt) {
                int row = dt * 16 + l15;
                int g1 = (ks * 4 + (quad >> 1)) ^ (row & 7);
                int base = row * 64 + (quad & 1) * 4;
                union { uint2 u2[2]; bf16x8 v; } vfu;
                vfu.u2[0] = *(const uint2*)&sVc[base + g1 * 8];
                vfu.u2[1] = *(const uint2*)&sVc[base + (g1 ^ 2) * 8];
#pragma unroll
                for (int nt = 0; nt < 2; ++nt)
                    oc[dt][nt] = __builtin_amdgcn_mfma_f32_16x16x32_bf16(
                        vfu.v, pf[ks][nt], oc[dt][nt], 0, 0, 0);
            }
        }

        __syncthreads();    // all reads of cur done; next-tile stages drained
        cur ^= 1;
    }

    // ---- finalize: cross-quad l sum, normalize, store O bf16 ----
    float il[2];
#pragma unroll
    for (int mt = 0; mt < 2; ++mt) {
        float ls = l_r[mt];
        ls += __shfl_xor(ls, 16);
        ls += __shfl_xor(ls, 32);
        il[mt] = 1.f / ls;
    }
#pragma unroll
    for (int nt = 0; nt < 2; ++nt)
#pragma unroll
        for (int dt = 0; dt < 8; ++dt) {
            union { u16 u[4]; uint2 v; } pk;
#pragma unroll
            for (int r = 0; r < 4; ++r) pk.u[r] = f2bf(oc[dt][nt][r] * il[nt]);
            *(uint2*)(O + (size_t)(q0 + w * 32 + nt * 16 + l15) * HIDDEN
                        + h * HD + dt * 16 + quad * 4) = pk.v;
        }
}

// ---------------- host ----------------
extern "C" void kernel_launch(void* const* d_in, const int* in_sizes, int n_in,
                              void* d_out, int out_size, void* d_ws, size_t ws_size,
                              hipStream_t stream) {
    const float* hs = (const float*)d_in[0];
    const int* pos  = (const int*)d_in[1];
    const float* wq = (const float*)d_in[2];
    const float* wk = (const float*)d_in[3];
    const float* wv = (const float*)d_in[4];
    const float* wo = (const float*)d_in[5];
    float* out = (float*)d_out;

    u16* ws    = (u16*)d_ws;
    u16* qb    = ws;
    u16* kb    = qb + (size_t)S_LEN * HIDDEN;
    u16* vt    = kb + (size_t)S_LEN * NKV * HD;
    u16* at    = vt + (size_t)S_LEN * NKV * HD;
    float2* tab = (float2*)(at + (size_t)S_LEN * HIDDEN);

    dim3 blk(256);

    // RoPE table first (gemm_qkv k-path consumes it in-epilogue)
    DTab dt;
    for (int i = 0; i < 64; ++i) dt.f[i] = pow(500000.0, -(double)i / 64.0);
    rope_table<<<dim3(S_LEN * 64 / 256), blk, 0, stream>>>(pos, tab, dt);

    // fused QKV projection, f32-direct operands (V transposed; K rope'd in epilogue)
    gemm_qkv<<<dim3((HIDDEN + 2 * NKV * HD) / 128, S_LEN / 128), blk, 0, stream>>>(
        hs, wq, wk, wv, qb, kb, vt, tab);

    const float qscale = 0.08838834764831845f * 1.4426950408889634f; // sm_scale*log2e
    attn_kernel<<<dim3(S_LEN / 128, NH), dim3(256), 0, stream>>>(
        qb, kb, vt, at, tab, qscale);

    gemm_bt_f32<<<dim3(HIDDEN / 128, S_LEN / 128), blk, 0, stream>>>(
        at, wo, out, HIDDEN, HIDDEN);
}